// Round 7
// baseline (520.291 us; speedup 1.0000x reference)
//
#include <hip/hip_runtime.h>
#include <hip/hip_bf16.h>
#include <math.h>

#define D_MODEL 1024
#define FFN_DIM 4096
#define NHEAD 16
#define DK 64
#define BATCH 16
#define SEQ 512
#define ROWS (BATCH * SEQ) /* 8192 */
#define QKV_N 3072

typedef short short8 __attribute__((ext_vector_type(8)));
typedef float f32x4 __attribute__((ext_vector_type(4)));

__device__ __forceinline__ float bf2f(short s) {
    return __uint_as_float(((unsigned)(unsigned short)s) << 16);
}
__device__ __forceinline__ short f2bf(float f) {
    unsigned u = __float_as_uint(f);
    u += 0x7fff + ((u >> 16) & 1);   // round-to-nearest-even
    return (short)(u >> 16);
}

// XOR-swizzled index into a [rows][64] bf16 tile (8-elem blocks kept contiguous)
__device__ __forceinline__ int swz(int row, int col) {
    int s = (row ^ (row >> 3)) & 7;
    return row * 64 + ((((col >> 3) ^ s) << 3) | (col & 7));
}

// async 16B global -> LDS (wave-uniform LDS base + lane*16)
__device__ __forceinline__ void gll16(const short* g, short* l) {
    __builtin_amdgcn_global_load_lds(
        (const __attribute__((address_space(1))) unsigned int*)g,
        (__attribute__((address_space(3))) unsigned int*)l, 16, 0, 0);
}

// ---------------------------------------------------------------------------
// Weight preshuffle: W[K][N] fp32 -> frag-major bf16.
// Frag f = (n/16)*(K/32) + (k/32); lane = (klocal/8)*16 + n%16 holds 8
// consecutive k elems -> B-frag load in GEMM = one coalesced 1KB read.
// grid = (N/16, K/128), 256 thr (4 frags per block).
// ---------------------------------------------------------------------------
__global__ __launch_bounds__(256) void convShuf(const float* __restrict__ in,
                                                short* __restrict__ out,
                                                int K, int N) {
    const int tid = threadIdx.x;
    const int lane = tid & 63, fl = tid >> 6;
    const int lm = lane & 15, quad = lane >> 4;
    const int nt = blockIdx.x;
    const int kc = blockIdx.y * 4 + fl;
    const int n = nt * 16 + lm;
    const int kb = kc * 32 + quad * 8;
    short8 v;
#pragma unroll
    for (int j = 0; j < 8; ++j) v[j] = f2bf(in[(size_t)(kb + j) * N + n]);
    *(short8*)&out[((size_t)nt * (K / 32) + kc) * 512 + lane * 8] = v;
}

// ---------------------------------------------------------------------------
// LayerNorm over 1024 elems, one block (256 thr) per row, bf16 output
// ---------------------------------------------------------------------------
__global__ __launch_bounds__(256) void ln_kernel(const float* __restrict__ x,
                                                 const float* __restrict__ g,
                                                 const float* __restrict__ beta,
                                                 short* __restrict__ out) {
    const int row = blockIdx.x;
    const int tid = threadIdx.x;
    const float4 xv = ((const float4*)(x + (size_t)row * D_MODEL))[tid];
    float s  = xv.x + xv.y + xv.z + xv.w;
    float s2 = xv.x * xv.x + xv.y * xv.y + xv.z * xv.z + xv.w * xv.w;
#pragma unroll
    for (int off = 32; off >= 1; off >>= 1) {
        s  += __shfl_down(s, off);
        s2 += __shfl_down(s2, off);
    }
    __shared__ float red[8];
    if ((tid & 63) == 0) { red[(tid >> 6) * 2] = s; red[(tid >> 6) * 2 + 1] = s2; }
    __syncthreads();
    s  = red[0] + red[2] + red[4] + red[6];
    s2 = red[1] + red[3] + red[5] + red[7];
    const float mu  = s * (1.0f / D_MODEL);
    const float var = s2 * (1.0f / D_MODEL) - mu * mu;
    const float r   = rsqrtf(var + 1e-5f);
    const int c = tid * 4;
    short4 ov;
    ov.x = f2bf((xv.x - mu) * r * g[c + 0] + beta[c + 0]);
    ov.y = f2bf((xv.y - mu) * r * g[c + 1] + beta[c + 1]);
    ov.z = f2bf((xv.z - mu) * r * g[c + 2] + beta[c + 2]);
    ov.w = f2bf((xv.w - mu) * r * g[c + 3] + beta[c + 3]);
    *(short4*)(out + (size_t)row * D_MODEL + c) = ov;
}

// ---------------------------------------------------------------------------
// bf16 MFMA GEMM, B from preshuffled frag-major global (never in LDS):
// C[M,N] = A[M,K] @ W. 128x256 block tile, 4 waves (2x2), wave tile 64x128
// (4 m-frags x 8 n-frags), BK=64. A: XOR-swizzled LDS, double-buffered,
// global_load_lds width-16. B: direct coalesced 1KB frag loads (L1/L2-hot).
// MODE 0: out bf16; MODE 1: fp32 = acc+bias+resid; MODE 2: bf16 = gelu_tanh(acc+bias)
// ---------------------------------------------------------------------------
template <int MODE>
__global__ __launch_bounds__(256, 2) void gemm128(
    const short* __restrict__ A, const short* __restrict__ Bp,
    int M, int N, int K, int ldc,
    const float* __restrict__ bias, const float* __restrict__ resid,
    float* __restrict__ outf, short* __restrict__ outb) {
    __shared__ __align__(16) short As[2][128 * 64];
    const int tid = threadIdx.x;
    const int w = tid >> 6, lane = tid & 63;
    const int lm = lane & 15, quad = lane >> 4;
    const int m0 = blockIdx.y * 128, n0 = blockIdx.x * 256;
    const int wm = (w & 1) * 64, wn = (w >> 1) * 128;
    const int KC = K / 32;

    // A staging: call j covers rows j*32 + w*8 .. +7; lane -> (row=lane>>3,
    // lds chunk = lane&7); global k-chunk XOR-permuted to match swizzle.
    const int srl = lane >> 3;
    const int gch = (lane & 7) ^ srl;
    const short* gA[4];
    int lofs[4];
#pragma unroll
    for (int j = 0; j < 4; ++j) {
        const int row = j * 32 + w * 8 + srl;
        gA[j] = A + (size_t)(m0 + row) * K + gch * 8;
        lofs[j] = (j * 32 + w * 8) * 64;
    }

    // B frag pointers: frag (nt, kc) at Bp + (nt*KC + kc)*512 + lane*8
    const short* bptr[8];
#pragma unroll
    for (int nn = 0; nn < 8; ++nn)
        bptr[nn] = Bp + ((size_t)((n0 + wn) / 16 + nn) * KC) * 512 + lane * 8;

    f32x4 acc[4][8];
#pragma unroll
    for (int i = 0; i < 4; ++i)
#pragma unroll
        for (int j = 0; j < 8; ++j) acc[i][j] = (f32x4){0.f, 0.f, 0.f, 0.f};

    // prologue: stage k0=0 into buffer 0
#pragma unroll
    for (int j = 0; j < 4; ++j) gll16(gA[j], &As[0][lofs[j]]);

    int buf = 0;
    for (int k0 = 0; k0 < K; k0 += 64) {
        __syncthreads();   // drains vmcnt -> buf ready
        if (k0 + 64 < K) {
#pragma unroll
            for (int j = 0; j < 4; ++j) gll16(gA[j] + k0 + 64, &As[buf ^ 1][lofs[j]]);
        }
#pragma unroll
        for (int kk = 0; kk < 2; ++kk) {
            const int kc = (k0 >> 5) + kk;
            short8 af[4], bfr[8];
#pragma unroll
            for (int nn = 0; nn < 8; ++nn)
                bfr[nn] = *(const short8*)(bptr[nn] + (size_t)kc * 512);
#pragma unroll
            for (int mm = 0; mm < 4; ++mm) {
                const int row = wm + mm * 16 + lm;
                const int ch = (kk * 4 + quad) ^ (row & 7);
                af[mm] = *(short8*)&As[buf][row * 64 + ch * 8];
            }
#pragma unroll
            for (int mm = 0; mm < 4; ++mm)
#pragma unroll
                for (int nn = 0; nn < 8; ++nn)
                    acc[mm][nn] = __builtin_amdgcn_mfma_f32_16x16x32_bf16(
                        af[mm], bfr[nn], acc[mm][nn], 0, 0, 0);
        }
        buf ^= 1;
    }

#pragma unroll
    for (int mm = 0; mm < 4; ++mm)
#pragma unroll
        for (int nn = 0; nn < 8; ++nn)
#pragma unroll
            for (int r = 0; r < 4; ++r) {
                const int row = m0 + wm + mm * 16 + quad * 4 + r;
                const int col = n0 + wn + nn * 16 + lm;
                const float vv = acc[mm][nn][r];
                if (MODE == 0) {
                    outb[(size_t)row * ldc + col] = f2bf(vv);
                } else if (MODE == 1) {
                    outf[(size_t)row * ldc + col] =
                        vv + bias[col] + resid[(size_t)row * ldc + col];
                } else {
                    const float gv = vv + bias[col];
                    const float u = 0.7978845608f * gv * (1.0f + 0.044715f * gv * gv);
                    const float ge = gv / (1.0f + __expf(-2.0f * u));
                    outb[(size_t)row * ldc + col] = f2bf(ge);
                }
            }
}

// ---------------------------------------------------------------------------
// MFMA causal flash attention over fused QKV buffer [ROWS][3072].
// Block = 128 q-rows x head x batch, 256 thr; wave w owns q rows w*32..+31.
// ---------------------------------------------------------------------------
__global__ __launch_bounds__(256) void attn_mfma(const short* __restrict__ qkv,
                                                 short* __restrict__ o) {
    __shared__ __align__(16) short Ks[64 * 64];     // [j][d] swizzled
    __shared__ __align__(16) short Vt[64 * 64];     // [d][j] swizzled
    __shared__ __align__(16) short Ps[4][32 * 64];  // per-wave [m][j] swizzled

    const int tid = threadIdx.x;
    const int qt = blockIdx.x, h = blockIdx.y, b = blockIdx.z;
    const int w = tid >> 6, lane = tid & 63;
    const int lm = lane & 15, quad = lane >> 4;

    const int sj  = tid >> 2;          // staging row 0..63
    const int sd0 = (tid & 3) * 16;    // staging d-chunk

    short8 aq[2][2];
#pragma unroll
    for (int m = 0; m < 2; ++m) {
        const short* qrow =
            qkv + (size_t)(b * SEQ + qt * 128 + w * 32 + m * 16 + lm) * QKV_N + h * DK;
#pragma unroll
        for (int kk = 0; kk < 2; ++kk) {
            short8 raw = *(const short8*)(qrow + kk * 32 + quad * 8);
            short8 sc;
#pragma unroll
            for (int j = 0; j < 8; ++j) sc[j] = f2bf(bf2f(raw[j]) * 0.125f);
            aq[m][kk] = sc;
        }
    }

    f32x4 accO[2][4];
#pragma unroll
    for (int m = 0; m < 2; ++m)
#pragma unroll
        for (int i = 0; i < 4; ++i) accO[m][i] = (f32x4){0.f, 0.f, 0.f, 0.f};
    float mrow[2][4], lrow[2][4];
#pragma unroll
    for (int m = 0; m < 2; ++m)
#pragma unroll
        for (int r = 0; r < 4; ++r) { mrow[m][r] = -1e30f; lrow[m][r] = 0.f; }

    short* pw = Ps[w];
    const int ktmax = 2 * qt + 1;

    for (int kt = 0; kt <= ktmax; ++kt) {
        __syncthreads();
        {
            const short* ksrc =
                qkv + (size_t)(b * SEQ + kt * 64 + sj) * QKV_N + D_MODEL + h * DK + sd0;
            short8 k0v = *(const short8*)ksrc;
            short8 k1v = *(const short8*)(ksrc + 8);
            *(short8*)&Ks[swz(sj, sd0)]     = k0v;
            *(short8*)&Ks[swz(sj, sd0 + 8)] = k1v;
            const short* vsrc =
                qkv + (size_t)(b * SEQ + kt * 64 + sj) * QKV_N + 2 * D_MODEL + h * DK + sd0;
            short8 v0v = *(const short8*)vsrc;
            short8 v1v = *(const short8*)(vsrc + 8);
#pragma unroll
            for (int dd = 0; dd < 8; ++dd) Vt[swz(sd0 + dd, sj)]     = v0v[dd];
#pragma unroll
            for (int dd = 0; dd < 8; ++dd) Vt[swz(sd0 + 8 + dd, sj)] = v1v[dd];
        }
        __syncthreads();

        bool live[2];
#pragma unroll
        for (int m = 0; m < 2; ++m) {
            const int rowmin = qt * 128 + w * 32 + m * 16;
            live[m] = (kt * 64 <= rowmin + 15);
            if (!live[m]) continue;
            const bool needmask = (kt * 64 + 63 > rowmin);

            f32x4 sacc[4];
#pragma unroll
            for (int nn = 0; nn < 4; ++nn) sacc[nn] = (f32x4){0.f, 0.f, 0.f, 0.f};
#pragma unroll
            for (int kk = 0; kk < 2; ++kk)
#pragma unroll
                for (int nn = 0; nn < 4; ++nn) {
                    short8 bfrag = *(short8*)&Ks[swz(nn * 16 + lm, kk * 32 + quad * 8)];
                    sacc[nn] = __builtin_amdgcn_mfma_f32_16x16x32_bf16(
                        aq[m][kk], bfrag, sacc[nn], 0, 0, 0);
                }

            if (needmask) {
#pragma unroll
                for (int nn = 0; nn < 4; ++nn) {
                    const int kg = kt * 64 + nn * 16 + lm;
#pragma unroll
                    for (int r = 0; r < 4; ++r) {
                        const int qg = rowmin + quad * 4 + r;
                        if (kg > qg) sacc[nn][r] = -1e30f;
                    }
                }
            }

            float mnew[4], alpha[4], rsum[4];
#pragma unroll
            for (int r = 0; r < 4; ++r) {
                float mx = fmaxf(fmaxf(sacc[0][r], sacc[1][r]),
                                 fmaxf(sacc[2][r], sacc[3][r]));
#pragma unroll
                for (int msk = 1; msk <= 8; msk <<= 1) mx = fmaxf(mx, __shfl_xor(mx, msk));
                mnew[r] = fmaxf(mrow[m][r], mx);
                alpha[r] = __expf(mrow[m][r] - mnew[r]);
                rsum[r] = 0.f;
            }
#pragma unroll
            for (int nn = 0; nn < 4; ++nn)
#pragma unroll
                for (int r = 0; r < 4; ++r) {
                    const float p = __expf(sacc[nn][r] - mnew[r]);
                    sacc[nn][r] = p;
                    rsum[r] += p;
                }
#pragma unroll
            for (int r = 0; r < 4; ++r) {
#pragma unroll
                for (int msk = 1; msk <= 8; msk <<= 1) rsum[r] += __shfl_xor(rsum[r], msk);
                lrow[m][r] = lrow[m][r] * alpha[r] + rsum[r];
                mrow[m][r] = mnew[r];
            }
#pragma unroll
            for (int nn = 0; nn < 4; ++nn)
#pragma unroll
                for (int r = 0; r < 4; ++r) accO[m][nn][r] *= alpha[r];

#pragma unroll
            for (int nn = 0; nn < 4; ++nn)
#pragma unroll
                for (int r = 0; r < 4; ++r)
                    pw[swz(m * 16 + quad * 4 + r, nn * 16 + lm)] = f2bf(sacc[nn][r]);
        }

#pragma unroll
        for (int kk = 0; kk < 2; ++kk) {
            short8 bfr[4];
#pragma unroll
            for (int nn = 0; nn < 4; ++nn)
                bfr[nn] = *(short8*)&Vt[swz(nn * 16 + lm, kk * 32 + quad * 8)];
#pragma unroll
            for (int m = 0; m < 2; ++m) {
                if (!live[m]) continue;
                short8 afrag = *(short8*)&pw[swz(m * 16 + lm, kk * 32 + quad * 8)];
#pragma unroll
                for (int nn = 0; nn < 4; ++nn)
                    accO[m][nn] = __builtin_amdgcn_mfma_f32_16x16x32_bf16(
                        afrag, bfr[nn], accO[m][nn], 0, 0, 0);
            }
        }
    }

#pragma unroll
    for (int m = 0; m < 2; ++m)
#pragma unroll
        for (int r = 0; r < 4; ++r) {
            const float invl = 1.0f / lrow[m][r];
            const int row = b * SEQ + qt * 128 + w * 32 + m * 16 + quad * 4 + r;
#pragma unroll
            for (int nn = 0; nn < 4; ++nn)
                o[(size_t)row * D_MODEL + h * DK + nn * 16 + lm] =
                    f2bf(accO[m][nn][r] * invl);
        }
}

// ---------------------------------------------------------------------------
// launcher
// ---------------------------------------------------------------------------
extern "C" void kernel_launch(void* const* d_in, const int* in_sizes, int n_in,
                              void* d_out, int out_size, void* d_ws, size_t ws_size,
                              hipStream_t stream) {
    const float* x     = (const float*)d_in[0];
    const float* ln1_g = (const float*)d_in[1];
    const float* ln1_b = (const float*)d_in[2];
    const float* w_q   = (const float*)d_in[3];
    const float* w_k   = (const float*)d_in[4];
    const float* w_v   = (const float*)d_in[5];
    const float* w_o   = (const float*)d_in[6];
    const float* b_o   = (const float*)d_in[7];
    const float* ln2_g = (const float*)d_in[8];
    const float* ln2_b = (const float*)d_in[9];
    const float* w1    = (const float*)d_in[10];
    const float* b1    = (const float*)d_in[11];
    const float* w2    = (const float*)d_in[12];
    const float* b2    = (const float*)d_in[13];
    float* out = (float*)d_out;

    char* ws = (char*)d_ws;
    size_t off = 0;
    auto alloc = [&](size_t bytes) {
        char* p = ws + off;
        off += (bytes + 255) & ~(size_t)255;
        return p;
    };
    short* h_bf   = (short*)alloc((size_t)ROWS * D_MODEL * 2);  // 16 MB
    short* qkv_bf = (short*)alloc((size_t)ROWS * QKV_N * 2);    // 48 MB
    short* a_bf   = (short*)alloc((size_t)ROWS * D_MODEL * 2);  // 16 MB (adjacent to qkv)
    float* x1     = (float*)alloc((size_t)ROWS * D_MODEL * 4);  // 32 MB
    short* wqkvP  = (short*)alloc((size_t)QKV_N * D_MODEL * 2); // preshuffled
    short* woP    = (short*)alloc((size_t)D_MODEL * D_MODEL * 2);
    short* w1P    = (short*)alloc((size_t)D_MODEL * FFN_DIM * 2);
    short* w2P    = (short*)alloc((size_t)FFN_DIM * D_MODEL * 2);
    short* g1_bf  = qkv_bf;  // [8192][4096] bf16 = 64 MB, spans qkv_bf + a_bf

    // preshuffle weights to frag-major bf16 (re-run every launch; ws re-poisoned)
    const int KC1 = D_MODEL / 32;   // 32 chunks for K=1024
    convShuf<<<dim3(D_MODEL / 16, D_MODEL / 128), 256, 0, stream>>>(
        w_q, wqkvP, D_MODEL, D_MODEL);
    convShuf<<<dim3(D_MODEL / 16, D_MODEL / 128), 256, 0, stream>>>(
        w_k, wqkvP + (size_t)64 * KC1 * 512, D_MODEL, D_MODEL);
    convShuf<<<dim3(D_MODEL / 16, D_MODEL / 128), 256, 0, stream>>>(
        w_v, wqkvP + (size_t)128 * KC1 * 512, D_MODEL, D_MODEL);
    convShuf<<<dim3(D_MODEL / 16, D_MODEL / 128), 256, 0, stream>>>(
        w_o, woP, D_MODEL, D_MODEL);
    convShuf<<<dim3(FFN_DIM / 16, D_MODEL / 128), 256, 0, stream>>>(
        w1, w1P, D_MODEL, FFN_DIM);
    convShuf<<<dim3(D_MODEL / 16, FFN_DIM / 128), 256, 0, stream>>>(
        w2, w2P, FFN_DIM, D_MODEL);

    // LN1
    ln_kernel<<<ROWS, 256, 0, stream>>>(x, ln1_g, ln1_b, h_bf);

    // fused QKV projection: [8192][3072]
    gemm128<0><<<dim3(QKV_N / 256, ROWS / 128), 256, 0, stream>>>(
        h_bf, wqkvP, ROWS, QKV_N, D_MODEL, QKV_N,
        nullptr, nullptr, nullptr, qkv_bf);

    // attention (128 q-rows per block)
    attn_mfma<<<dim3(SEQ / 128, NHEAD, BATCH), 256, 0, stream>>>(qkv_bf, a_bf);

    // output projection + bias + residual -> x1 (fp32)
    gemm128<1><<<dim3(D_MODEL / 256, ROWS / 128), 256, 0, stream>>>(
        a_bf, woP, ROWS, D_MODEL, D_MODEL, D_MODEL, b_o, x, x1, nullptr);

    // LN2
    ln_kernel<<<ROWS, 256, 0, stream>>>(x1, ln2_g, ln2_b, h_bf);

    // FFN1 + tanh-GELU -> g1_bf
    gemm128<2><<<dim3(FFN_DIM / 256, ROWS / 128), 256, 0, stream>>>(
        h_bf, w1P, ROWS, FFN_DIM, D_MODEL, FFN_DIM, b1, nullptr, nullptr, g1_bf);

    // FFN2 + bias + residual -> out
    gemm128<1><<<dim3(D_MODEL / 256, ROWS / 128), 256, 0, stream>>>(
        g1_bf, w2P, ROWS, D_MODEL, FFN_DIM, D_MODEL, b2, x1, out, nullptr);
}